// Round 13
// baseline (398.968 us; speedup 1.0000x reference)
//
#include <hip/hip_runtime.h>

typedef _Float16 f16;
typedef __attribute__((ext_vector_type(4))) _Float16 f16x4;
typedef __attribute__((ext_vector_type(8))) _Float16 f16x8;
typedef __attribute__((ext_vector_type(4))) float f32x4;

__device__ __forceinline__ void fsplit(float v, f16& h, f16& l) {
  h = (f16)v;
  l = (f16)(v - (float)h);
}
__device__ __forceinline__ float fast_tanh(float x) {
  float ax = fabsf(x);
  float e = __expf(2.0f * ax);
  float r = 1.0f - 2.0f / (e + 1.0f);
  return copysignf(r, x);
}

#define GLD16(g, l) __builtin_amdgcn_global_load_lds( \
    (const __attribute__((address_space(1))) unsigned int*)(g), \
    (__attribute__((address_space(3))) unsigned int*)(l), 16, 0, 0)

// XCD-aware block swizzle (bijective: all grids % 8 == 0).
__device__ __forceinline__ void xcd_swz(int& bx, int& by, int& bz) {
  const int gx = gridDim.x, gy = gridDim.y;
  const int nwg = gx * gy * gridDim.z;
  const int flat = blockIdx.x + gx * (blockIdx.y + gy * blockIdx.z);
  const int virt = (flat & 7) * (nwg >> 3) + (flat >> 3);
  bx = virt % gx;
  const int rest = virt / gx;
  by = rest % gy;
  bz = rest / gy;
}

struct GemmArgs {
  const f16* Ah; const f16* Al; int lda; long long sA;
  const f16* Bh; const f16* Bl; int ldb; long long sB;
  f16* Ch; f16* Cl; int ldc; long long sC;
  const float* wh; float* z;
  int btr;   // 1: B is [K][N] row-major (L); reg-staged transpose into LDS
};

// ---------------------------------------------------------------------------
// Split-fp16 MFMA GEMM: D = A*B^T. A[M][K] hi/lo. B: btr=0 -> B[N][K] via
// global_load_lds (slot = kg ^ (row&3), pre-swizzled global src); btr=1 ->
// B[K][N] (L[t][n]) loaded to regs (coalesced rows) and ds_write'd with
// slot = ks ^ ((row>>3)&3) (4-way write conflict; round-12 verified).
// SINGLE-buffered 32KB LDS (4 planes x 8KB), 2 barriers per K-step — halves
// LDS vs dbuf so 4-5 blocks/CU can be resident (was 2): the big dispatches
// are latency-bound at 17% occupancy, not BW-bound (z: HBM 8%, L2-resident).
// 128x128 tile, BK=32, 4 waves, 4x4 frags of 16x16x32 MFMA, 3-product split
// AhBh+AhBl+AlBh (~2^-23 rel).
// EPI 0: store hi/lo.  EPI 1: tanh -> store hi/lo. (epilogue image staged in
// two 64-row halves to fit 32KB)  EPI 2: z[n] = sum_m wh[m]*tanh(acc+bias).
// NSETS=1: m0=by*128. NSETS=2: by selects set, m0=0.
// NSETS=3: by<2 -> sets 0/1 (m0=0,n0=bx*128); by>=2 -> set 2 M=512,N=256
// (m0=((by-2)*2+(bx>>1))*128, n0=(bx&1)*128).
// ---------------------------------------------------------------------------
template<int EPI, int NSETS>
__global__ __launch_bounds__(256, 4) void mgemm(GemmArgs g0, GemmArgs g1,
                                                GemmArgs g2, int Kd)
{
  __shared__ char smem[32768];
  int bx, by, bz;
  xcd_swz(bx, by, bz);
  const GemmArgs* gp;
  int m0, n0;
  if (NSETS == 3) {
    if (by < 2) { gp = by ? &g1 : &g0; m0 = 0; n0 = bx * 128; }
    else { gp = &g2; m0 = ((by - 2) * 2 + (bx >> 1)) * 128; n0 = (bx & 1) * 128; }
  } else if (NSETS == 2) {
    gp = by ? &g1 : &g0; m0 = 0; n0 = bx * 128;
  } else {
    gp = &g0; m0 = by * 128; n0 = bx * 128;
  }
  const GemmArgs& g = *gp;
  const int b = bz;
  const int tid = threadIdx.x;
  const int lane = tid & 63;
  const int wid = tid >> 6;
  const int wrow = (wid >> 1) * 64, wcol = (wid & 1) * 64;
  const int lda = g.lda, ldb = g.ldb;
  const bool btr = g.btr != 0;

  const f16* Agh = g.Ah + (long long)b * g.sA;
  const f16* Agl = g.Al + (long long)b * g.sA;
  const f16* Bgh = g.Bh + (long long)b * g.sB;
  const f16* Bgl = g.Bl + (long long)b * g.sB;

  f32x4 acc[4][4];
#pragma unroll
  for (int i = 0; i < 4; ++i)
#pragma unroll
    for (int j = 0; j < 4; ++j) acc[i][j] = f32x4{0.f, 0.f, 0.f, 0.f};

  // A staging / NT-B staging: thread -> (row = tid>>2 (+64), 16B slot = tid&3);
  // source k-slot pre-swizzled so LDS dest stays linear (tid*16B).
  const int srow = tid >> 2;
  const int sq = tid & 3;
  const int gs0 = ((sq ^ (srow & 3)) * 8);
  const long long gaA0 = (long long)(m0 + srow) * lda + gs0;
  const long long gaA1 = (long long)(m0 + srow + 64) * lda + gs0;
  const long long gaB0 = (long long)(n0 + srow) * ldb + gs0;
  const long long gaB1 = (long long)(n0 + srow + 64) * ldb + gs0;

  auto stageA = [&](int k0) {
    char* pAh = smem;
    char* pAl = smem + 8192;
    GLD16(Agh + gaA0 + k0, pAh + tid * 16);
    GLD16(Agh + gaA1 + k0, pAh + 4096 + tid * 16);
    GLD16(Agl + gaA0 + k0, pAl + tid * 16);
    GLD16(Agl + gaA1 + k0, pAl + 4096 + tid * 16);
  };
  auto stageBnt = [&](int k0) {
    char* pBh = smem + 16384;
    char* pBl = smem + 24576;
    GLD16(Bgh + gaB0 + k0, pBh + tid * 16);
    GLD16(Bgh + gaB1 + k0, pBh + 4096 + tid * 16);
    GLD16(Bgl + gaB0 + k0, pBl + tid * 16);
    GLD16(Bgl + gaB1 + k0, pBl + 4096 + tid * 16);
  };

  // btr: reg-staged transpose. thread -> btl = tid>>3 (k in 0..31),
  // bng = tid&7 (n-group). Load L[k0+btl][n0 + (bng+8h)*8 .. +7] (coalesced
  // 128B per 8 lanes); scatter: hw(row) = row*32 + (ks^((row>>3)&3))*8 + pos.
  const int btl = tid >> 3;
  const int bng = tid & 7;
  auto loadB = [&](int k0, f16x8* vh, f16x8* vl) {
#pragma unroll
    for (int h = 0; h < 2; ++h) {
      const long long o = (long long)(k0 + btl) * ldb + n0 + (bng + h * 8) * 8;
      vh[h] = *(const f16x8*)&Bgh[o];
      vl[h] = *(const f16x8*)&Bgl[o];
    }
  };
  auto writeB = [&](const f16x8* vh, const f16x8* vl) {
    f16* pBh = (f16*)(smem + 16384);
    f16* pBl = (f16*)(smem + 24576);
    const int ks = btl >> 3, pos = btl & 7;
#pragma unroll
    for (int h = 0; h < 2; ++h) {
      const int ng = bng + h * 8;
      const int slot = ks ^ (ng & 3);
#pragma unroll
      for (int e = 0; e < 8; ++e) {
        const int row = ng * 8 + e;
        const int hw = row * 32 + slot * 8 + pos;
        pBh[hw] = vh[h][e];
        pBl[hw] = vl[h][e];
      }
    }
  };

  // frag read offsets; B slot function matches the staging mode
  const int rl = lane & 15, kg = lane >> 4;
  int aoff[4], boff[4];
#pragma unroll
  for (int i = 0; i < 4; ++i) {
    int rowa = wrow + i * 16 + rl;
    aoff[i] = rowa * 32 + ((kg ^ (rowa & 3)) * 8);
    int rowb = wcol + i * 16 + rl;
    int slotb = btr ? (kg ^ ((rowb >> 3) & 3)) : (kg ^ (rowb & 3));
    boff[i] = rowb * 32 + slotb * 8;
  }

  const int nt = Kd >> 5;
  f16x8 vbh[2], vbl[2];
  for (int t = 0; t < nt; ++t) {
    stageA(t * 32);
    if (btr) { loadB(t * 32, vbh, vbl); writeB(vbh, vbl); }
    else stageBnt(t * 32);
    __syncthreads();   // drains vmcnt (gload_lds) + lgkm (ds_writes): data visible

    const f16* sAh = (const f16*)smem;
    const f16* sAl = (const f16*)(smem + 8192);
    const f16* sBh = (const f16*)(smem + 16384);
    const f16* sBl = (const f16*)(smem + 24576);
    f16x8 fah[4], fal[4], fbh[4], fbl[4];
#pragma unroll
    for (int i = 0; i < 4; ++i) {
      fah[i] = *(const f16x8*)&sAh[aoff[i]];
      fal[i] = *(const f16x8*)&sAl[aoff[i]];
      fbh[i] = *(const f16x8*)&sBh[boff[i]];
      fbl[i] = *(const f16x8*)&sBl[boff[i]];
    }
#pragma unroll
    for (int i = 0; i < 4; ++i)
#pragma unroll
      for (int j = 0; j < 4; ++j) {
        acc[i][j] = __builtin_amdgcn_mfma_f32_16x16x32_f16(fah[i], fbh[j], acc[i][j], 0, 0, 0);
        acc[i][j] = __builtin_amdgcn_mfma_f32_16x16x32_f16(fah[i], fbl[j], acc[i][j], 0, 0, 0);
        acc[i][j] = __builtin_amdgcn_mfma_f32_16x16x32_f16(fal[i], fbh[j], acc[i][j], 0, 0, 0);
      }
    __syncthreads();   // all reads done before next iter overwrites buffer
  }

  // C/D layout (measured, m89): col = lane&15, row = (lane>>4)*4 + reg
  if (EPI <= 1) {
    f16x4 ph[4][4], pl[4][4];
#pragma unroll
    for (int i = 0; i < 4; ++i)
#pragma unroll
      for (int j = 0; j < 4; ++j)
#pragma unroll
        for (int q = 0; q < 4; ++q) {
          float v = (EPI == 1) ? fast_tanh(acc[i][j][q]) : acc[i][j][q];
          f16 h, l; fsplit(v, h, l);
          ph[i][j][q] = h; pl[i][j][q] = l;
        }
    f16* img = (f16*)smem;            // [64][136] half-image (17408 B)
    const int q4 = lane >> 4, c16 = lane & 15;
#pragma unroll
    for (int lo = 0; lo < 2; ++lo) {
      f16* gb = (lo ? g.Cl : g.Ch) + (long long)b * g.sC;
#pragma unroll
      for (int half = 0; half < 2; ++half) {
        __syncthreads();
        if ((wrow >> 6) == half) {
#pragma unroll
          for (int i = 0; i < 4; ++i)
#pragma unroll
            for (int j = 0; j < 4; ++j)
#pragma unroll
              for (int q = 0; q < 4; ++q)
                img[(i * 16 + kg * 4 + q) * 136 + wcol + j * 16 + rl] =
                    lo ? pl[i][j][q] : ph[i][j][q];
        }
        __syncthreads();
#pragma unroll
        for (int it = 0; it < 4; ++it) {
          int rloc = it * 16 + wid * 4 + q4;
          int r = half * 64 + rloc;
          *(f16x8*)&gb[(long long)(m0 + r) * g.ldc + n0 + c16 * 8] =
              *(const f16x8*)&img[rloc * 136 + c16 * 8];
        }
      }
    }
  } else {
    const f16* bh = g.Ch + (long long)b * g.sC;
    const f16* bl = g.Cl + (long long)b * g.sC;
    const int ldc = g.ldc;
    float zp[4] = {0.f, 0.f, 0.f, 0.f};
#pragma unroll
    for (int i = 0; i < 4; ++i)
#pragma unroll
      for (int q = 0; q < 4; ++q) {
        int grow = m0 + wrow + i * 16 + kg * 4 + q;
        float wv = g.wh[grow];
#pragma unroll
        for (int j = 0; j < 4; ++j) {
          int gcol = n0 + wcol + j * 16 + rl;
          long long bi = (long long)grow * ldc + gcol;
          float bias = (float)bh[bi] + (float)bl[bi];
          zp[j] += wv * fast_tanh(acc[i][j][q] + bias);
        }
      }
#pragma unroll
    for (int j = 0; j < 4; ++j) {
      zp[j] += __shfl_xor(zp[j], 16);
      zp[j] += __shfl_xor(zp[j], 32);
    }
    __syncthreads();
    float* zred = (float*)smem;
    if (lane < 16) {
#pragma unroll
      for (int j = 0; j < 4; ++j)
        zred[(wid >> 1) * 128 + wcol + j * 16 + lane] = zp[j];
    }
    __syncthreads();
    if (tid < 128)
      g.z[(long long)b * 512 + n0 + tid] = zred[tid] + zred[128 + tid];
  }
}

// ---------------------------------------------------------------------------
__global__ void cvt_hilo2(const float* __restrict__ s0, f16* __restrict__ h0,
                          f16* __restrict__ l0_,
                          const float* __restrict__ s1, f16* __restrict__ h1,
                          f16* __restrict__ l1_, int n4)
{
  const float* src = blockIdx.y ? s1 : s0;
  f16* hi = blockIdx.y ? h1 : h0;
  f16* lo = blockIdx.y ? l1_ : l0_;
  int stride = gridDim.x * blockDim.x;
  for (int i = blockIdx.x * blockDim.x + threadIdx.x; i < n4; i += stride) {
    f32x4 v = ((const f32x4*)src)[i];
    f16x4 h, l;
#pragma unroll
    for (int c = 0; c < 4; ++c) {
      f16 hh, ll;
      fsplit(v[c], hh, ll);
      h[c] = hh; l[c] = ll;
    }
    ((f16x4*)hi)[i] = h;
    ((f16x4*)lo)[i] = l;
  }
}

__global__ void prep_weights(const float* __restrict__ Wl, const float* __restrict__ Ws,
                             const float* __restrict__ Wc, const float* __restrict__ whs,
                             const float* __restrict__ whc,
                             f16* __restrict__ WlT_hi, f16* __restrict__ WlT_lo,
                             f16* __restrict__ Ws2_hi, f16* __restrict__ Ws2_lo,
                             f16* __restrict__ Wc2_hi, f16* __restrict__ Wc2_lo,
                             float* __restrict__ whs2, float* __restrict__ whc2)
{
  const int blk = blockIdx.x, t = threadIdx.x;
  if (blk < 256) {            // WlT[D][d] = Wl[d][D]
    f16 h, l;
    fsplit(Wl[t * 256 + blk], h, l);
    WlT_hi[blk * 256 + t] = h;
    WlT_lo[blk * 256 + t] = l;
  } else if (blk < 384) {     // Ws padded K 80->128
    int k = blk - 256;
    f16 h, l;
    fsplit((k < 80) ? Ws[k * 256 + t] : 0.f, h, l);
    Ws2_hi[k * 256 + t] = h;
    Ws2_lo[k * 256 + t] = l;
  } else if (blk < 512) {     // Wc padded
    int k = blk - 384;
    f16 h, l;
    fsplit((k < 80) ? Wc[k * 256 + t] : 0.f, h, l);
    Wc2_hi[k * 256 + t] = h;
    Wc2_lo[k * 256 + t] = l;
  } else {
    if (t < 128) whs2[t] = (t < 80) ? whs[t] : 0.f;
    else { int k = t - 128; whc2[k] = (k < 80) ? whc[k] : 0.f; }
  }
}

// Per-chunk softmax + pooling; X planes are the chunk's f16-hi inputs.
__global__ __launch_bounds__(256) void finalize(
    const f16* __restrict__ content_h, const f16* __restrict__ comments_h,
    const float* __restrict__ zs_c, const float* __restrict__ zc_c,
    float* __restrict__ out_c)
{
  const int b = blockIdx.x;
  const int half = blockIdx.y;
  const int tid = threadIdx.x;
  __shared__ float w[512];
  __shared__ float red[256];
  const float* z = (half ? zc_c : zs_c) + b * 512;
  const f16* X = (half ? comments_h : content_h) + (long long)b * 512 * 256;
  float v0 = z[tid], v1 = z[tid + 256];
  red[tid] = fmaxf(v0, v1);
  __syncthreads();
  for (int s = 128; s > 0; s >>= 1) {
    if (tid < s) red[tid] = fmaxf(red[tid], red[tid + s]);
    __syncthreads();
  }
  float mx = red[0];
  __syncthreads();
  float e0 = __expf(v0 - mx), e1 = __expf(v1 - mx);
  red[tid] = e0 + e1;
  __syncthreads();
  for (int s = 128; s > 0; s >>= 1) {
    if (tid < s) red[tid] += red[tid + s];
    __syncthreads();
  }
  float inv = 1.0f / red[0];
  w[tid] = e0 * inv;
  w[tid + 256] = e1 * inv;
  __syncthreads();
  float acc2 = 0.f;
  for (int r = 0; r < 512; ++r)
    acc2 = fmaf(w[r], (float)X[(long long)r * 256 + tid], acc2);
  out_c[(long long)b * 512 + half * 256 + tid] = acc2;
}

// ---------------------------------------------------------------------------
extern "C" void kernel_launch(void* const* d_in, const int* in_sizes, int n_in,
                              void* d_out, int out_size, void* d_ws, size_t ws_size,
                              hipStream_t stream) {
  (void)in_sizes; (void)n_in; (void)out_size;
  const float* content  = (const float*)d_in[0];
  const float* comments = (const float*)d_in[1];
  const float* Wl  = (const float*)d_in[2];
  const float* Wc  = (const float*)d_in[3];
  const float* Ws  = (const float*)d_in[4];
  const float* whs = (const float*)d_in[5];
  const float* whc = (const float*)d_in[6];
  float* out = (float*)d_out;

  const long long PBcm = 512 * 256;   // per-batch elems, content/comments
  const long long PBL  = 512 * 512;   // per-batch elems, L
  const long long PBsc = 128 * 512;   // per-batch elems, Sc / Cc

  // per-batch ws: c/m 4 planes (1 MiB) + CW 0.5 + Sc/Cc 0.5 + L 1 = 3.0 MiB
  const size_t perG = 3145728;
  int G = 16;
  if      (ws_size >= 64 * perG + (4ULL << 20)) G = 64;
  else if (ws_size >= 32 * perG + (4ULL << 20)) G = 32;

  char* base = (char*)d_ws;
  size_t off = 0;
  auto alloc = [&](size_t bytes) -> char* {
    char* p = base + off;
    off = (off + bytes + 255) & ~(size_t)255;
    return p;
  };

  // chunked planes
  f16* c_hi  = (f16*)alloc((size_t)G * PBcm * 2);
  f16* c_lo  = (f16*)alloc((size_t)G * PBcm * 2);
  f16* m_hi  = (f16*)alloc((size_t)G * PBcm * 2);
  f16* m_lo  = (f16*)alloc((size_t)G * PBcm * 2);
  f16* CW_hi = (f16*)alloc((size_t)G * PBcm * 2);
  f16* CW_lo = (f16*)alloc((size_t)G * PBcm * 2);
  f16* Sc_hi = (f16*)alloc((size_t)G * PBsc * 2);
  f16* Sc_lo = (f16*)alloc((size_t)G * PBsc * 2);
  f16* Cc_hi = (f16*)alloc((size_t)G * PBsc * 2);
  f16* Cc_lo = (f16*)alloc((size_t)G * PBsc * 2);
  f16* L_hi  = (f16*)alloc((size_t)G * PBL * 2);
  f16* L_lo  = (f16*)alloc((size_t)G * PBL * 2);
  // fixed
  f16* WlT_hi = (f16*)alloc(256 * 256 * 2);
  f16* WlT_lo = (f16*)alloc(256 * 256 * 2);
  f16* Ws2_hi = (f16*)alloc(128 * 256 * 2);
  f16* Ws2_lo = (f16*)alloc(128 * 256 * 2);
  f16* Wc2_hi = (f16*)alloc(128 * 256 * 2);
  f16* Wc2_lo = (f16*)alloc(128 * 256 * 2);
  float* whs2 = (float*)alloc(512);
  float* whc2 = (float*)alloc(512);
  float* zs = (float*)alloc(128 * 512 * 4);
  float* zc = (float*)alloc(128 * 512 * 4);

  dim3 blk(256);

  prep_weights<<<dim3(513), blk, 0, stream>>>(Wl, Ws, Wc, whs, whc,
      WlT_hi, WlT_lo, Ws2_hi, Ws2_lo, Wc2_hi, Wc2_lo, whs2, whc2);

  for (int c0 = 0; c0 < 128; c0 += G) {
    // 1. convert this chunk's inputs to hi/lo f16
    cvt_hilo2<<<dim3(1024, 2), blk, 0, stream>>>(
        content + (long long)c0 * PBcm, c_hi, c_lo,
        comments + (long long)c0 * PBcm, m_hi, m_lo,
        (int)((long long)G * PBcm / 4));

    GemmArgs sc, cc, cw, zA, zB;

    // 2+4+5 merged (all EPI=0, K=256, 16 blocks/batch -> 1024-block grid):
    //   set0: Sc = Ws2 @ content^T   set1: Cc = Wc2 @ comments^T
    //   set2: CW = comments @ Wl
    sc = {Ws2_hi, Ws2_lo, 256, 0,  c_hi, c_lo, 256, PBcm,
          Sc_hi, Sc_lo, 512, PBsc,  nullptr, nullptr, 0};
    cc = {Wc2_hi, Wc2_lo, 256, 0,  m_hi, m_lo, 256, PBcm,
          Cc_hi, Cc_lo, 512, PBsc,  nullptr, nullptr, 0};
    cw = {m_hi, m_lo, 256, PBcm,  WlT_hi, WlT_lo, 256, 0,
          CW_hi, CW_lo, 256, PBcm,  nullptr, nullptr, 0};
    mgemm<0, 3><<<dim3(4, 4, G), blk, 0, stream>>>(sc, cc, cw, 256);

    // 3. L = tanh(CW @ content^T) -> L[t][n] hi/lo only (no LT)
    zA = {CW_hi, CW_lo, 256, PBcm,  c_hi, c_lo, 256, PBcm,
          L_hi, L_lo, 512, PBL,  nullptr, nullptr, 0};
    mgemm<1, 1><<<dim3(4, 4, G), blk, 0, stream>>>(zA, zA, zA, 256);

    // 6+7. merged z (K=512); both halves read the SAME L buffer:
    //   y=0 (btr=1): zs[n] = sum_k whs[k] tanh(Sc[k,n] + sum_t Cc[k,t] L[t,n])
    //   y=1 (btr=0): zc[t] = sum_k whc[k] tanh(Cc[k,t] + sum_n Sc[k,n] L[t,n])
    zA = {Cc_hi, Cc_lo, 512, PBsc,  L_hi, L_lo, 512, PBL,
          Sc_hi, Sc_lo, 512, PBsc,  whs2, zs + (long long)c0 * 512, 1};
    zB = {Sc_hi, Sc_lo, 512, PBsc,  L_hi, L_lo, 512, PBL,
          Cc_hi, Cc_lo, 512, PBsc,  whc2, zc + (long long)c0 * 512, 0};
    mgemm<2, 2><<<dim3(4, 2, G), blk, 0, stream>>>(zA, zB, zA, 512);

    // 8. per-chunk softmax + pooling (chunk's f16-hi planes still live)
    finalize<<<dim3(G, 2), blk, 0, stream>>>(
        c_hi, m_hi, zs + (long long)c0 * 512, zc + (long long)c0 * 512,
        out + (long long)c0 * 512);
  }
}

// Round 14
// 332.158 us; speedup vs baseline: 1.2011x; 1.2011x over previous
//
#include <hip/hip_runtime.h>

typedef _Float16 f16;
typedef __attribute__((ext_vector_type(4))) _Float16 f16x4;
typedef __attribute__((ext_vector_type(8))) _Float16 f16x8;
typedef __attribute__((ext_vector_type(4))) float f32x4;

__device__ __forceinline__ void fsplit(float v, f16& h, f16& l) {
  h = (f16)v;
  l = (f16)(v - (float)h);
}
__device__ __forceinline__ float fast_tanh(float x) {
  float ax = fabsf(x);
  float e = __expf(2.0f * ax);
  float r = 1.0f - 2.0f / (e + 1.0f);
  return copysignf(r, x);
}

#define GLD16(g, l) __builtin_amdgcn_global_load_lds( \
    (const __attribute__((address_space(1))) unsigned int*)(g), \
    (__attribute__((address_space(3))) unsigned int*)(l), 16, 0, 0)

// XCD-aware block swizzle: each XCD gets a contiguous range of virtual tiles
// (consecutive virt share A-panels -> L2 hits). Bijective: all grids % 8 == 0.
__device__ __forceinline__ void xcd_swz(int& bx, int& by, int& bz) {
  const int gx = gridDim.x, gy = gridDim.y;
  const int nwg = gx * gy * gridDim.z;
  const int flat = blockIdx.x + gx * (blockIdx.y + gy * blockIdx.z);
  const int virt = (flat & 7) * (nwg >> 3) + (flat >> 3);
  bx = virt % gx;
  const int rest = virt / gx;
  by = rest % gy;
  bz = rest / gy;
}

struct GemmArgs {
  const f16* Ah; const f16* Al; int lda; long long sA;
  const f16* Bh; const f16* Bl; int ldb; long long sB;
  f16* Ch; f16* Cl; int ldc; long long sC;
  f16* Th; f16* Tl; int ldt; long long sT;
  const float* wh; float* z;
};

// ---------------------------------------------------------------------------
// Split-fp16 MFMA GEMM: D = A*B^T, A[M][K] hi/lo, B[N][K] hi/lo (both NT).
// 128x128 tile, BK=32, 4 waves (2x2 of 64x64), 4x4 frags of 16x16x32 MFMA.
// 3-product split: AhBh + AhBl + AlBh  (rel err ~2^-23, near-f32).
// K-loop: 2-phase LDS double-buffer (2x32KB), prefetch next tile's
// global_load_lds before compute, ONE __syncthreads per step (its vmcnt(0)
// drain doubles as prefetch-completion wait).
// Epilogues: acc -> f16 hi/lo regs once, then per output plane stage through
// a padded LDS image [128][136] and store f16x8/lane, 256B-contig per row.
// EPI 0: store hi/lo.  EPI 1: tanh -> store hi/lo + transposed hi/lo.
// EPI 2: z[n] = sum_m wh[m]*tanh(acc + bias[m][n]); bias via Ch/Cl.
// NSETS=2: by selects operand set (merged small GEMMs), m0=0.
// ---------------------------------------------------------------------------
template<int EPI, int NSETS>
__global__ __launch_bounds__(256, 2) void mgemm(GemmArgs g0, GemmArgs g1, int Kd)
{
  __shared__ char smem[65536];   // 2 x (4 planes x 8KB) staging; epilogue image
  int bx, by, bz;
  xcd_swz(bx, by, bz);
  const GemmArgs& g = (NSETS == 2 && by == 1) ? g1 : g0;
  const int b = bz;
  const int m0 = (NSETS == 2) ? 0 : by * 128;
  const int n0 = bx * 128;
  const int tid = threadIdx.x;
  const int lane = tid & 63;
  const int wid = tid >> 6;
  const int wrow = (wid >> 1) * 64, wcol = (wid & 1) * 64;
  const int lda = g.lda, ldb = g.ldb;

  const f16* Agh = g.Ah + (long long)b * g.sA;
  const f16* Agl = g.Al + (long long)b * g.sA;
  const f16* Bgh = g.Bh + (long long)b * g.sB;
  const f16* Bgl = g.Bl + (long long)b * g.sB;

  f32x4 acc[4][4];
#pragma unroll
  for (int i = 0; i < 4; ++i)
#pragma unroll
    for (int j = 0; j < 4; ++j) acc[i][j] = f32x4{0.f, 0.f, 0.f, 0.f};

  // staging: thread -> (row = tid>>2 (+64), 16B slot = tid&3); source k-slot
  // pre-swizzled so LDS dest stays linear (tid*16B).
  const int srow = tid >> 2;
  const int sq = tid & 3;
  const int gs0 = ((sq ^ (srow & 3)) * 8);
  const long long gaA0 = (long long)(m0 + srow) * lda + gs0;
  const long long gaA1 = (long long)(m0 + srow + 64) * lda + gs0;
  const long long gaB0 = (long long)(n0 + srow) * ldb + gs0;
  const long long gaB1 = (long long)(n0 + srow + 64) * ldb + gs0;

  auto stage = [&](int k0, int bo) {
    char* pAh = smem + bo;
    char* pAl = smem + bo + 8192;
    char* pBh = smem + bo + 16384;
    char* pBl = smem + bo + 24576;
    GLD16(Agh + gaA0 + k0, pAh + tid * 16);
    GLD16(Agh + gaA1 + k0, pAh + 4096 + tid * 16);
    GLD16(Agl + gaA0 + k0, pAl + tid * 16);
    GLD16(Agl + gaA1 + k0, pAl + 4096 + tid * 16);
    GLD16(Bgh + gaB0 + k0, pBh + tid * 16);
    GLD16(Bgh + gaB1 + k0, pBh + 4096 + tid * 16);
    GLD16(Bgl + gaB0 + k0, pBl + tid * 16);
    GLD16(Bgl + gaB1 + k0, pBl + 4096 + tid * 16);
  };

  // frag read offsets (swizzled slot = kg ^ (row&3)), f16 elements
  const int rl = lane & 15, kg = lane >> 4;
  int aoff[4], boff[4];
#pragma unroll
  for (int i = 0; i < 4; ++i) {
    int rowa = wrow + i * 16 + rl;
    aoff[i] = rowa * 32 + ((kg ^ (rowa & 3)) * 8);
    int rowb = wcol + i * 16 + rl;
    boff[i] = rowb * 32 + ((kg ^ (rowb & 3)) * 8);
  }

  const int nt = Kd >> 5;
  int bufo = 0;
  stage(0, 0);
  __syncthreads();
  for (int t = 0; t < nt; ++t) {
    const int nb = bufo ^ 32768;
    if (t + 1 < nt) stage((t + 1) * 32, nb);   // prefetch overlaps compute

    const f16* sAh = (const f16*)(smem + bufo);
    const f16* sAl = (const f16*)(smem + bufo + 8192);
    const f16* sBh = (const f16*)(smem + bufo + 16384);
    const f16* sBl = (const f16*)(smem + bufo + 24576);
    f16x8 fah[4], fal[4], fbh[4], fbl[4];
#pragma unroll
    for (int i = 0; i < 4; ++i) {
      fah[i] = *(const f16x8*)&sAh[aoff[i]];
      fal[i] = *(const f16x8*)&sAl[aoff[i]];
      fbh[i] = *(const f16x8*)&sBh[boff[i]];
      fbl[i] = *(const f16x8*)&sBl[boff[i]];
    }
#pragma unroll
    for (int i = 0; i < 4; ++i)
#pragma unroll
      for (int j = 0; j < 4; ++j) {
        acc[i][j] = __builtin_amdgcn_mfma_f32_16x16x32_f16(fah[i], fbh[j], acc[i][j], 0, 0, 0);
        acc[i][j] = __builtin_amdgcn_mfma_f32_16x16x32_f16(fah[i], fbl[j], acc[i][j], 0, 0, 0);
        acc[i][j] = __builtin_amdgcn_mfma_f32_16x16x32_f16(fal[i], fbh[j], acc[i][j], 0, 0, 0);
      }
    __syncthreads();   // vmcnt(0) drain = prefetch landed; buffers swap safely
    bufo = nb;
  }

  // C/D layout (measured, m89): col = lane&15, row = (lane>>4)*4 + reg
  if (EPI <= 1) {
    // pack hi/lo f16 planes into registers once
    f16x4 ph[4][4], pl[4][4];
#pragma unroll
    for (int i = 0; i < 4; ++i)
#pragma unroll
      for (int j = 0; j < 4; ++j)
#pragma unroll
        for (int q = 0; q < 4; ++q) {
          float v = (EPI == 1) ? fast_tanh(acc[i][j][q]) : acc[i][j][q];
          f16 h, l; fsplit(v, h, l);
          ph[i][j][q] = h; pl[i][j][q] = l;
        }
    f16* img = (f16*)smem;            // [128][136] padded image
    const int q4 = lane >> 4, c16 = lane & 15;
    const int nplanes = (EPI == 1) ? 4 : 2;
#pragma unroll
    for (int plane = 0; plane < 4; ++plane) {
      if (plane >= nplanes) break;
      const int lo = plane & 1, tr = plane >> 1;
      __syncthreads();                // image free (previous reads done)
      if (!tr) {                      // [row=t][col=n]
#pragma unroll
        for (int i = 0; i < 4; ++i)
#pragma unroll
          for (int j = 0; j < 4; ++j)
#pragma unroll
            for (int q = 0; q < 4; ++q)
              img[(wrow + i * 16 + kg * 4 + q) * 136 + wcol + j * 16 + rl] =
                  lo ? pl[i][j][q] : ph[i][j][q];
      } else {                        // transposed image [row=n][col=t]
#pragma unroll
        for (int i = 0; i < 4; ++i)
#pragma unroll
          for (int j = 0; j < 4; ++j)
            *(f16x4*)&img[(wcol + j * 16 + rl) * 136 + wrow + i * 16 + kg * 4] =
                lo ? pl[i][j] : ph[i][j];
      }
      __syncthreads();
      f16* gb; int grow0, gcol0, ldg;
      if (!tr) { gb = (lo ? g.Cl : g.Ch) + (long long)b * g.sC; grow0 = m0; gcol0 = n0; ldg = g.ldc; }
      else     { gb = (lo ? g.Tl : g.Th) + (long long)b * g.sT; grow0 = n0; gcol0 = m0; ldg = g.ldt; }
#pragma unroll
      for (int it = 0; it < 8; ++it) {
        int r = it * 16 + wid * 4 + q4;
        *(f16x8*)&gb[(long long)(grow0 + r) * ldg + gcol0 + c16 * 8] =
            *(const f16x8*)&img[r * 136 + c16 * 8];
      }
    }
  } else {
    const f16* bh = g.Ch + (long long)b * g.sC;
    const f16* bl = g.Cl + (long long)b * g.sC;
    const int ldc = g.ldc;
    float zp[4] = {0.f, 0.f, 0.f, 0.f};
#pragma unroll
    for (int i = 0; i < 4; ++i)
#pragma unroll
      for (int q = 0; q < 4; ++q) {
        int grow = m0 + wrow + i * 16 + kg * 4 + q;
        float wv = g.wh[grow];
#pragma unroll
        for (int j = 0; j < 4; ++j) {
          int gcol = n0 + wcol + j * 16 + rl;
          long long bi = (long long)grow * ldc + gcol;
          float bias = (float)bh[bi] + (float)bl[bi];
          zp[j] += wv * fast_tanh(acc[i][j][q] + bias);
        }
      }
#pragma unroll
    for (int j = 0; j < 4; ++j) {  // reduce the 4 kg-lanes sharing a column
      zp[j] += __shfl_xor(zp[j], 16);
      zp[j] += __shfl_xor(zp[j], 32);
    }
    __syncthreads();
    float* zred = (float*)smem;
    if (lane < 16) {
#pragma unroll
      for (int j = 0; j < 4; ++j)
        zred[(wid >> 1) * 128 + wcol + j * 16 + lane] = zp[j];
    }
    __syncthreads();
    if (tid < 128)
      g.z[(long long)b * 512 + n0 + tid] = zred[tid] + zred[128 + tid];
  }
}

// ---------------------------------------------------------------------------
__global__ void cvt_hilo2(const float* __restrict__ s0, f16* __restrict__ h0,
                          f16* __restrict__ l0_,
                          const float* __restrict__ s1, f16* __restrict__ h1,
                          f16* __restrict__ l1_, int n4)
{
  const float* src = blockIdx.y ? s1 : s0;
  f16* hi = blockIdx.y ? h1 : h0;
  f16* lo = blockIdx.y ? l1_ : l0_;
  int stride = gridDim.x * blockDim.x;
  for (int i = blockIdx.x * blockDim.x + threadIdx.x; i < n4; i += stride) {
    f32x4 v = ((const f32x4*)src)[i];
    f16x4 h, l;
#pragma unroll
    for (int c = 0; c < 4; ++c) {
      f16 hh, ll;
      fsplit(v[c], hh, ll);
      h[c] = hh; l[c] = ll;
    }
    ((f16x4*)hi)[i] = h;
    ((f16x4*)lo)[i] = l;
  }
}

__global__ void prep_weights(const float* __restrict__ Wl, const float* __restrict__ Ws,
                             const float* __restrict__ Wc, const float* __restrict__ whs,
                             const float* __restrict__ whc,
                             f16* __restrict__ WlT_hi, f16* __restrict__ WlT_lo,
                             f16* __restrict__ Ws2_hi, f16* __restrict__ Ws2_lo,
                             f16* __restrict__ Wc2_hi, f16* __restrict__ Wc2_lo,
                             float* __restrict__ whs2, float* __restrict__ whc2)
{
  const int blk = blockIdx.x, t = threadIdx.x;
  if (blk < 256) {            // WlT[D][d] = Wl[d][D]
    f16 h, l;
    fsplit(Wl[t * 256 + blk], h, l);
    WlT_hi[blk * 256 + t] = h;
    WlT_lo[blk * 256 + t] = l;
  } else if (blk < 384) {     // Ws padded K 80->128
    int k = blk - 256;
    f16 h, l;
    fsplit((k < 80) ? Ws[k * 256 + t] : 0.f, h, l);
    Ws2_hi[k * 256 + t] = h;
    Ws2_lo[k * 256 + t] = l;
  } else if (blk < 512) {     // Wc padded
    int k = blk - 384;
    f16 h, l;
    fsplit((k < 80) ? Wc[k * 256 + t] : 0.f, h, l);
    Wc2_hi[k * 256 + t] = h;
    Wc2_lo[k * 256 + t] = l;
  } else {
    if (t < 128) whs2[t] = (t < 80) ? whs[t] : 0.f;
    else { int k = t - 128; whc2[k] = (k < 80) ? whc[k] : 0.f; }
  }
}

// Per-chunk softmax + pooling; X planes are the chunk's f16-hi inputs.
__global__ __launch_bounds__(256) void finalize(
    const f16* __restrict__ content_h, const f16* __restrict__ comments_h,
    const float* __restrict__ zs_c, const float* __restrict__ zc_c,
    float* __restrict__ out_c)
{
  const int b = blockIdx.x;          // local chunk batch
  const int half = blockIdx.y;
  const int tid = threadIdx.x;
  __shared__ float w[512];
  __shared__ float red[256];
  const float* z = (half ? zc_c : zs_c) + b * 512;
  const f16* X = (half ? comments_h : content_h) + (long long)b * 512 * 256;
  float v0 = z[tid], v1 = z[tid + 256];
  red[tid] = fmaxf(v0, v1);
  __syncthreads();
  for (int s = 128; s > 0; s >>= 1) {
    if (tid < s) red[tid] = fmaxf(red[tid], red[tid + s]);
    __syncthreads();
  }
  float mx = red[0];
  __syncthreads();
  float e0 = __expf(v0 - mx), e1 = __expf(v1 - mx);
  red[tid] = e0 + e1;
  __syncthreads();
  for (int s = 128; s > 0; s >>= 1) {
    if (tid < s) red[tid] += red[tid + s];
    __syncthreads();
  }
  float inv = 1.0f / red[0];
  w[tid] = e0 * inv;
  w[tid + 256] = e1 * inv;
  __syncthreads();
  float acc2 = 0.f;
  for (int r = 0; r < 512; ++r)
    acc2 = fmaf(w[r], (float)X[(long long)r * 256 + tid], acc2);
  out_c[(long long)b * 512 + half * 256 + tid] = acc2;
}

// ---------------------------------------------------------------------------
extern "C" void kernel_launch(void* const* d_in, const int* in_sizes, int n_in,
                              void* d_out, int out_size, void* d_ws, size_t ws_size,
                              hipStream_t stream) {
  (void)in_sizes; (void)n_in; (void)out_size;
  const float* content  = (const float*)d_in[0];
  const float* comments = (const float*)d_in[1];
  const float* Wl  = (const float*)d_in[2];
  const float* Wc  = (const float*)d_in[3];
  const float* Ws  = (const float*)d_in[4];
  const float* whs = (const float*)d_in[5];
  const float* whc = (const float*)d_in[6];
  float* out = (float*)d_out;

  const long long PBcm = 512 * 256;   // per-batch elems, content/comments
  const long long PBL  = 512 * 512;   // per-batch elems, L / LT
  const long long PBsc = 128 * 512;   // per-batch elems, Sc / Cc

  // per-batch chunked ws: c/m 4 planes (1 MiB) + CW(=Sc/Cc alias) 0.5 MiB
  //                       + L 1 MiB + LT 1 MiB = 3.5 MiB; fixed ~1.2 MiB.
  const size_t perG = 3670016;   // 3.5 MiB
  int G = 16;
  if      (ws_size >= 64 * perG + (4ULL << 20)) G = 64;
  else if (ws_size >= 32 * perG + (4ULL << 20)) G = 32;

  char* base = (char*)d_ws;
  size_t off = 0;
  auto alloc = [&](size_t bytes) -> char* {
    char* p = base + off;
    off = (off + bytes + 255) & ~(size_t)255;
    return p;
  };

  // chunked planes
  f16* c_hi  = (f16*)alloc((size_t)G * PBcm * 2);
  f16* c_lo  = (f16*)alloc((size_t)G * PBcm * 2);
  f16* m_hi  = (f16*)alloc((size_t)G * PBcm * 2);
  f16* m_lo  = (f16*)alloc((size_t)G * PBcm * 2);
  f16* CW_hi = (f16*)alloc((size_t)G * PBcm * 2);
  f16* CW_lo = (f16*)alloc((size_t)G * PBcm * 2);
  f16* L_hi  = (f16*)alloc((size_t)G * PBL * 2);
  f16* L_lo  = (f16*)alloc((size_t)G * PBL * 2);
  f16* LT_hi = (f16*)alloc((size_t)G * PBL * 2);
  f16* LT_lo = (f16*)alloc((size_t)G * PBL * 2);
  // Sc/Cc alias the CW region (CW dead after step 3; 4*G*PBsc == 2*G*PBcm)
  f16* Sc_hi = CW_hi;
  f16* Sc_lo = Sc_hi + (size_t)G * PBsc;
  f16* Cc_hi = Sc_lo + (size_t)G * PBsc;
  f16* Cc_lo = Cc_hi + (size_t)G * PBsc;
  // fixed
  f16* WlT_hi = (f16*)alloc(256 * 256 * 2);
  f16* WlT_lo = (f16*)alloc(256 * 256 * 2);
  f16* Ws2_hi = (f16*)alloc(128 * 256 * 2);
  f16* Ws2_lo = (f16*)alloc(128 * 256 * 2);
  f16* Wc2_hi = (f16*)alloc(128 * 256 * 2);
  f16* Wc2_lo = (f16*)alloc(128 * 256 * 2);
  float* whs2 = (float*)alloc(512);
  float* whc2 = (float*)alloc(512);
  float* zs = (float*)alloc(128 * 512 * 4);
  float* zc = (float*)alloc(128 * 512 * 4);

  dim3 blk(256);

  prep_weights<<<dim3(513), blk, 0, stream>>>(Wl, Ws, Wc, whs, whc,
      WlT_hi, WlT_lo, Ws2_hi, Ws2_lo, Wc2_hi, Wc2_lo, whs2, whc2);

  for (int c0 = 0; c0 < 128; c0 += G) {
    // 1. convert this chunk's inputs to hi/lo f16
    cvt_hilo2<<<dim3(1024, 2), blk, 0, stream>>>(
        content + (long long)c0 * PBcm, c_hi, c_lo,
        comments + (long long)c0 * PBcm, m_hi, m_lo,
        (int)((long long)G * PBcm / 4));

    GemmArgs a, b2;

    // 2. CW = comments @ Wl   (M=512, N=256, K=256)
    a = {m_hi, m_lo, 256, PBcm,  WlT_hi, WlT_lo, 256, 0,
         CW_hi, CW_lo, 256, PBcm,  nullptr, nullptr, 0, 0,  nullptr, nullptr};
    mgemm<0, 1><<<dim3(2, 4, G), blk, 0, stream>>>(a, a, 256);

    // 3. L = tanh(CW @ content^T) -> L[t][n] + LT[n][t], hi/lo
    a = {CW_hi, CW_lo, 256, PBcm,  c_hi, c_lo, 256, PBcm,
         L_hi, L_lo, 512, PBL,  LT_hi, LT_lo, 512, PBL,  nullptr, nullptr};
    mgemm<1, 1><<<dim3(4, 4, G), blk, 0, stream>>>(a, a, 256);

    // 4+5. Sc = Ws2 @ content^T ; Cc = Wc2 @ comments^T  (merged via y;
    //      writes alias the dead CW region)
    a  = {Ws2_hi, Ws2_lo, 256, 0,  c_hi, c_lo, 256, PBcm,
          Sc_hi, Sc_lo, 512, PBsc,  nullptr, nullptr, 0, 0,  nullptr, nullptr};
    b2 = {Wc2_hi, Wc2_lo, 256, 0,  m_hi, m_lo, 256, PBcm,
          Cc_hi, Cc_lo, 512, PBsc,  nullptr, nullptr, 0, 0,  nullptr, nullptr};
    mgemm<0, 2><<<dim3(4, 2, G), blk, 0, stream>>>(a, b2, 256);

    // 6+7. zs[n] = sum_k whs[k] tanh(Sc[k,n] + Cc@LT) ;
    //      zc[t] = sum_k whc[k] tanh(Cc[k,t] + Sc@L)   (merged via y, K=512)
    a  = {Cc_hi, Cc_lo, 512, PBsc,  LT_hi, LT_lo, 512, PBL,
          Sc_hi, Sc_lo, 512, PBsc,  nullptr, nullptr, 0, 0,
          whs2, zs + (long long)c0 * 512};
    b2 = {Sc_hi, Sc_lo, 512, PBsc,  L_hi, L_lo, 512, PBL,
          Cc_hi, Cc_lo, 512, PBsc,  nullptr, nullptr, 0, 0,
          whc2, zc + (long long)c0 * 512};
    mgemm<2, 2><<<dim3(4, 2, G), blk, 0, stream>>>(a, b2, 512);

    // 8. per-chunk softmax + pooling, reading the chunk's f16-hi planes
    //    (still live; overwritten only by the next chunk's cvt)
    finalize<<<dim3(G, 2), blk, 0, stream>>>(
        c_hi, m_hi, zs + (long long)c0 * 512, zc + (long long)c0 * 512,
        out + (long long)c0 * 512);
  }
}